// Round 2
// baseline (363.522 us; speedup 1.0000x reference)
//
#include <hip/hip_runtime.h>
#include <math.h>

// Workspace layout (floats):
//   p3: pooled x3 (k=8)  -> [2][256][16][16] = 131,072 floats
//   p4: pooled x4 (k=16) -> [2][16][16]      =     512 floats
// total 526,336 bytes (fits per-XCD L2)
#define P3_OFF 0
#define P4_OFF (2 * 256 * 256)

__device__ __forceinline__ float fmax4(float4 v) {
    return fmaxf(fmaxf(v.x, v.y), fmaxf(v.z, v.w));
}

// Phase 1: pool x3 (k=8) and x4 (k=16) into ws. 514 blocks x 256 threads.
//   [0, 2)    : p4 (one block per batch), 16x16 pooling over 256x256
//   [2, 514)  : p3, 8x8 pooling over 128x128, ch = bid-2 flattens (b, c3)
__global__ void pool34_kernel(const float* __restrict__ x3,
                              const float* __restrict__ x4,
                              float* __restrict__ ws) {
    const int bid = blockIdx.x;
    const int t = threadIdx.x;          // 0..255
    const int h = t >> 4;
    const int w = t & 15;

    if (bid < 2) {
        const float* src = x4 + (size_t)bid * 65536 + (size_t)(h * 16) * 256 + w * 16;
        float m = -INFINITY;
#pragma unroll
        for (int r = 0; r < 16; ++r) {
            const float4* p = (const float4*)(src + (size_t)r * 256);
#pragma unroll
            for (int q = 0; q < 4; ++q) m = fmaxf(m, fmax4(p[q]));
        }
        ws[P4_OFF + bid * 256 + t] = m;
    } else {
        const int ch = bid - 2;         // 0..511 over (b, c3)
        const float* src = x3 + (size_t)ch * 16384 + (size_t)(h * 8) * 128 + w * 8;
        float m = -INFINITY;
#pragma unroll
        for (int r = 0; r < 8; ++r) {
            const float4* p = (const float4*)(src + (size_t)r * 128);
            m = fmaxf(m, fmaxf(fmax4(p[0]), fmax4(p[1])));
        }
        ws[P3_OFF + ch * 256 + t] = m;
    }
}

// Phase 2: block = (b, c2). 8192 blocks x 256 threads.
// Each block serves x1-channels c1 = c2 + 4096*j (j = wave id = t>>6), which
// all share: x2 channel (b,c2), p3 channel (b, c2&255), p4 map (b).
// Thread: u = t&63, h = u>>2, wq = u&3 -> owns pooled quad (h, 4wq..4wq+3).
// Per thread: inline 4x4-pool of x2 (L1-served, redundant across waves),
// inline 2x2-pool of x1[b,c1], add p3/p4 + ff, ReLU, write channels c1 and
// c1+16384.
__global__ void fuse_kernel(const float* __restrict__ x1,
                            const float* __restrict__ x2,
                            const float* __restrict__ ff,
                            const float* __restrict__ ws,
                            float* __restrict__ out) {
    const int bid = blockIdx.x;
    const int b = bid >> 12;
    const int c2 = bid & 4095;
    const int t = threadIdx.x;
    const int j = t >> 6;
    const int u = t & 63;
    const int h = u >> 2;
    const int wq = u & 3;
    const int c1 = c2 + 4096 * j;
    const int pos = h * 16 + wq * 4;    // float4 position in the 16x16 map

    // ---- inline 4x4 max-pool of x2[b, c2] (64x64) for this quad ----
    // pooled cols 4wq+c come from input cols 16wq+4c..16wq+4c+3, rows 4h..4h+3
    const float* src2 = x2 + ((size_t)(b * 4096 + c2)) * 4096 + (size_t)(4 * h) * 64 + 16 * wq;
    float4 v2 = make_float4(-INFINITY, -INFINITY, -INFINITY, -INFINITY);
#pragma unroll
    for (int r = 0; r < 4; ++r) {
        const float4* p = (const float4*)(src2 + (size_t)r * 64);
        v2.x = fmaxf(v2.x, fmax4(p[0]));
        v2.y = fmaxf(v2.y, fmax4(p[1]));
        v2.z = fmaxf(v2.z, fmax4(p[2]));
        v2.w = fmaxf(v2.w, fmax4(p[3]));
    }

    // ---- inline 2x2 max-pool of x1[b, c1] (32x32) for this quad ----
    const float* X1 = x1 + ((size_t)(b * 16384 + c1)) * 1024 + (size_t)(2 * h) * 32 + 8 * wq;
    const float4 a0 = ((const float4*)X1)[0];        // row 2h,   cols 8wq..+3
    const float4 b0 = ((const float4*)X1)[1];        // row 2h,   cols 8wq+4..+7
    const float4 a1 = ((const float4*)(X1 + 32))[0]; // row 2h+1
    const float4 b1 = ((const float4*)(X1 + 32))[1];
    float4 v1;
    v1.x = fmaxf(fmaxf(a0.x, a0.y), fmaxf(a1.x, a1.y));
    v1.y = fmaxf(fmaxf(a0.z, a0.w), fmaxf(a1.z, a1.w));
    v1.z = fmaxf(fmaxf(b0.x, b0.y), fmaxf(b1.x, b1.y));
    v1.w = fmaxf(fmaxf(b0.z, b0.w), fmaxf(b1.z, b1.w));

    // ---- pooled x3/x4 from workspace (L2-resident; same for all j) ----
    const float4 v3 = *(const float4*)(ws + P3_OFF + (size_t)(b * 256 + (c2 & 255)) * 256 + pos);
    const float4 v4 = *(const float4*)(ws + P4_OFF + (size_t)b * 256 + pos);

    // Match reference addition order: (((y1+y2)+y3)+y4)+ff
    float4 s;
    s.x = ((v1.x + v2.x) + v3.x) + v4.x;
    s.y = ((v1.y + v2.y) + v3.y) + v4.y;
    s.z = ((v1.z + v2.z) + v3.z) + v4.z;
    s.w = ((v1.w + v2.w) + v3.w) + v4.w;

    const size_t o1 = ((size_t)(b * 32768 + c1)) * 256 + pos;
    const size_t o2 = o1 + (size_t)16384 * 256;

    const float4 f1 = *(const float4*)(ff + o1);
    const float4 f2 = *(const float4*)(ff + o2);

    float4 r1, r2;
    r1.x = fmaxf(s.x + f1.x, 0.0f);
    r1.y = fmaxf(s.y + f1.y, 0.0f);
    r1.z = fmaxf(s.z + f1.z, 0.0f);
    r1.w = fmaxf(s.w + f1.w, 0.0f);
    r2.x = fmaxf(s.x + f2.x, 0.0f);
    r2.y = fmaxf(s.y + f2.y, 0.0f);
    r2.z = fmaxf(s.z + f2.z, 0.0f);
    r2.w = fmaxf(s.w + f2.w, 0.0f);

    *(float4*)(out + o1) = r1;
    *(float4*)(out + o2) = r2;
}

extern "C" void kernel_launch(void* const* d_in, const int* in_sizes, int n_in,
                              void* d_out, int out_size, void* d_ws, size_t ws_size,
                              hipStream_t stream) {
    const float* x1 = (const float*)d_in[0];  // [2,16384,32,32]
    const float* x2 = (const float*)d_in[1];  // [2,4096,64,64]
    const float* x3 = (const float*)d_in[2];  // [2,256,128,128]
    const float* x4 = (const float*)d_in[3];  // [2,1,256,256]
    const float* ff = (const float*)d_in[4];  // [2,32768,16,16]
    float* out = (float*)d_out;               // [2,32768,16,16]
    float* ws = (float*)d_ws;                 // needs 526,336 bytes

    // Phase 1: pool x3/x4 into workspace (32.5 MB read — tiny).
    pool34_kernel<<<514, 256, 0, stream>>>(x3, x4, ws);
    // Phase 2: fused x1+x2 pooling + sum + relu + channel-tiled stores.
    fuse_kernel<<<8192, 256, 0, stream>>>(x1, x2, ff, ws, out);
}

// Round 3
// 354.784 us; speedup vs baseline: 1.0246x; 1.0246x over previous
//
#include <hip/hip_runtime.h>
#include <math.h>

// Workspace layout (floats):
//   p2: pooled x2 (k=4)  -> [2][4096][16][16] = 2,097,152 floats
//   p3: pooled x3 (k=8)  -> [2][256][16][16]  =   131,072 floats
//   p4: pooled x4 (k=16) -> [2][16][16]       =       512 floats
// total 8,914,944 bytes (p2 is L2/L3-resident between phases)
#define P2_OFF 0
#define P3_OFF (2 * 4096 * 256)
#define P4_OFF (P3_OFF + 2 * 256 * 256)

__device__ __forceinline__ float fmax4(float4 v) {
    return fmaxf(fmaxf(v.x, v.y), fmaxf(v.z, v.w));
}

// Phase 1: pool x2 (k=4), x3 (k=8), x4 (k=16) into ws.
// Blocks: [0,2): p4 | [2,514): p3 | [514,8706): p2. 256 threads/block,
// thread t owns pooled element (h,w) = (t>>4, t&15).
__global__ void pool_all_kernel(const float* __restrict__ x2,
                                const float* __restrict__ x3,
                                const float* __restrict__ x4,
                                float* __restrict__ ws) {
    const int bid = blockIdx.x;
    const int t = threadIdx.x;
    const int h = t >> 4;
    const int w = t & 15;

    if (bid >= 514) {
        // p2: ch flattens (b, c2); 64x64 -> 16x16, window 4x4
        const int ch = bid - 514;
        const float* src = x2 + (size_t)ch * 4096 + (size_t)(4 * h) * 64 + 4 * w;
        const float4 r0 = *(const float4*)(src);
        const float4 r1 = *(const float4*)(src + 64);
        const float4 r2 = *(const float4*)(src + 128);
        const float4 r3 = *(const float4*)(src + 192);
        ws[P2_OFF + ch * 256 + t] =
            fmaxf(fmaxf(fmax4(r0), fmax4(r1)), fmaxf(fmax4(r2), fmax4(r3)));
    } else if (bid >= 2) {
        // p3: ch flattens (b, c3); 128x128 -> 16x16, window 8x8
        const int ch = bid - 2;
        const float* src = x3 + (size_t)ch * 16384 + (size_t)(8 * h) * 128 + 8 * w;
        float m = -INFINITY;
#pragma unroll
        for (int r = 0; r < 8; ++r) {
            const float4* p = (const float4*)(src + (size_t)r * 128);
            m = fmaxf(m, fmaxf(fmax4(p[0]), fmax4(p[1])));
        }
        ws[P3_OFF + ch * 256 + t] = m;
    } else {
        // p4: one block per batch; 256x256 -> 16x16, window 16x16
        const float* src = x4 + (size_t)bid * 65536 + (size_t)(16 * h) * 256 + 16 * w;
        float m = -INFINITY;
#pragma unroll
        for (int r = 0; r < 16; ++r) {
            const float4* p = (const float4*)(src + (size_t)r * 256);
#pragma unroll
            for (int q = 0; q < 4; ++q) m = fmaxf(m, fmax4(p[q]));
        }
        ws[P4_OFF + bid * 256 + t] = m;
    }
}

// Phase 2: block = (b, cg), cg in [0,4096). 8192 blocks x 256 threads.
// Wave j (=t>>6) handles x1 channel c1 = cg + 4096*j; all waves share
// p2[b,cg], p3[b,cg&255], p4[b] (L1-resident within the block).
// Thread u (=t&63): h = u>>2, wq = u&3 -> pooled float4 at (h, 4wq).
// 9 independent global loads issued up-front, then compute, then 2 stores
// (output channels c1 and c1+16384 share the pooled sum s).
__global__ void fuse_kernel(const float* __restrict__ x1,
                            const float* __restrict__ ff,
                            const float* __restrict__ ws,
                            float* __restrict__ out) {
    const int bid = blockIdx.x;
    const int b = bid >> 12;
    const int cg = bid & 4095;
    const int t = threadIdx.x;
    const int j = t >> 6;
    const int u = t & 63;
    const int h = u >> 2;
    const int wq = u & 3;
    const int c1 = cg + 4096 * j;
    const int pos = h * 16 + wq * 4;   // float4 position in the 16x16 map

    const float* X1 = x1 + ((size_t)(b * 16384 + c1)) * 1024 + (size_t)(2 * h) * 32 + 8 * wq;
    const size_t o1 = ((size_t)(b * 32768 + c1)) * 256 + pos;
    const size_t o2 = o1 + (size_t)16384 * 256;

    // ---- issue all 9 loads before any use ----
    const float4 a0 = ((const float4*)X1)[0];         // x1 row 2h,   cols 8wq..+3
    const float4 b0 = ((const float4*)X1)[1];         // x1 row 2h,   cols 8wq+4..+7
    const float4 a1 = ((const float4*)(X1 + 32))[0];  // x1 row 2h+1
    const float4 b1 = ((const float4*)(X1 + 32))[1];
    const float4 v2 = *(const float4*)(ws + P2_OFF + (size_t)(b * 4096 + cg) * 256 + pos);
    const float4 v3 = *(const float4*)(ws + P3_OFF + (size_t)(b * 256 + (cg & 255)) * 256 + pos);
    const float4 v4 = *(const float4*)(ws + P4_OFF + (size_t)b * 256 + pos);
    const float4 f1 = *(const float4*)(ff + o1);
    const float4 f2 = *(const float4*)(ff + o2);

    // ---- 2x2 max-pool of x1 ----
    float4 v1;
    v1.x = fmaxf(fmaxf(a0.x, a0.y), fmaxf(a1.x, a1.y));
    v1.y = fmaxf(fmaxf(a0.z, a0.w), fmaxf(a1.z, a1.w));
    v1.z = fmaxf(fmaxf(b0.x, b0.y), fmaxf(b1.x, b1.y));
    v1.w = fmaxf(fmaxf(b0.z, b0.w), fmaxf(b1.z, b1.w));

    // Match reference addition order: (((y1+y2)+y3)+y4)+ff
    float4 s;
    s.x = ((v1.x + v2.x) + v3.x) + v4.x;
    s.y = ((v1.y + v2.y) + v3.y) + v4.y;
    s.z = ((v1.z + v2.z) + v3.z) + v4.z;
    s.w = ((v1.w + v2.w) + v3.w) + v4.w;

    float4 r1, r2;
    r1.x = fmaxf(s.x + f1.x, 0.0f);
    r1.y = fmaxf(s.y + f1.y, 0.0f);
    r1.z = fmaxf(s.z + f1.z, 0.0f);
    r1.w = fmaxf(s.w + f1.w, 0.0f);
    r2.x = fmaxf(s.x + f2.x, 0.0f);
    r2.y = fmaxf(s.y + f2.y, 0.0f);
    r2.z = fmaxf(s.z + f2.z, 0.0f);
    r2.w = fmaxf(s.w + f2.w, 0.0f);

    *(float4*)(out + o1) = r1;
    *(float4*)(out + o2) = r2;
}

extern "C" void kernel_launch(void* const* d_in, const int* in_sizes, int n_in,
                              void* d_out, int out_size, void* d_ws, size_t ws_size,
                              hipStream_t stream) {
    const float* x1 = (const float*)d_in[0];  // [2,16384,32,32]
    const float* x2 = (const float*)d_in[1];  // [2,4096,64,64]
    const float* x3 = (const float*)d_in[2];  // [2,256,128,128]
    const float* x4 = (const float*)d_in[3];  // [2,1,256,256]
    const float* ff = (const float*)d_in[4];  // [2,32768,16,16]
    float* out = (float*)d_out;               // [2,32768,16,16]
    float* ws = (float*)d_ws;                 // needs 8,914,944 bytes

    // Phase 1: pool x2/x3/x4 into workspace (48.5 MB read, 9 MB write).
    pool_all_kernel<<<2 + 512 + 8192, 256, 0, stream>>>(x2, x3, x4, ws);
    // Phase 2: streaming fuse — 9 independent loads/thread, 2 stores.
    fuse_kernel<<<8192, 256, 0, stream>>>(x1, ff, ws, out);
}